// Round 20
// baseline (105.357 us; speedup 1.0000x reference)
//
#include <hip/hip_runtime.h>
#include <stdint.h>

// DNAS_DeformAxialDW: out = x + axial-deform-DW-conv_H(x) + axial-deform-DW-conv_W(x)
// Scalar fractional dilation r => each 7-tap conv folds into 13 integer taps with
// per-channel effective weights (precomputed into d_ws by taps_kernel).
//
// R18 90.8 BEST: producer-consumer wave split (1 producer wave stages, 7 waves
//     compute, one barrier/tile, dbuf 51KB, 3 blk/CU). No pipe >55%.
// R19 94.7: RPT=4/TH=32 full-W: dbuf 78,848x2 > usable LDS -> 1 blk/CU. BUT:
//     only 4.3% slower at 1/3 the waves => issue-limited, not occupancy-bound.
// R20: RPT=4 via W-SPLIT: block = plane x W-half (28 out quads + 2 halo quads
//     each side = 32 staged quads/row). Buffer 44x512B = 22,528 B, dbuf 45,056
//     -> 3 blk/CU. W-halo pre-staged WITH ZEROS at true edges => consumer
//     W-conv reads are unconditional (no cndmask). 8 LDS reads/output (-27%).
//     224 consumers (28cq x 8rg, waves 0-3) + producer wave 4, BLOCK=320.

namespace {
constexpr int B = 8, C = 128, H = 224, W = 224;
constexpr int KT = 7;              // original taps
constexpr int M  = 6;              // max |integer offset| (r in [1,2])
constexpr int NT = 2 * M + 1;      // 13 effective integer taps
constexpr int TH = 32;             // output rows per tile
constexpr int NTPB = 7;            // tiles per block (full plane height)
constexpr int SROWS = TH + 2 * M;  // 44 staged rows
constexpr int OQ = 28;             // output quads per block (W-half)
constexpr int SQ = 32;             // staged quads per row (2 halo each side)
constexpr int BLOCK = 320;         // waves 0-3 consumers (224 thr), wave 4 producer
constexpr int NCONS = 224;         // consumer threads
constexpr int RPT = 4;             // output rows per thread
constexpr int WROWS = RPT + 2 * M; // 16 window rows per thread
constexpr int RFLOATS = SQ * 4;    // 128 floats per LDS row (512 B)
constexpr int BUF_FLOATS = SROWS * RFLOATS;   // 5632 floats = 22,528 B
constexpr int LDS_FLOATS = 2 * BUF_FLOATS;    // 45,056 B -> 3 blocks/CU
constexpr int ZOFF = 2 * C * NT;   // zeros region offset in d_ws (floats) = 3328
}

typedef __attribute__((address_space(3))) uint32_t lds_u32;
typedef __attribute__((address_space(1))) const uint32_t gbl_u32;

// Fold bilinear fractional taps into integer-offset effective weights; also
// zero-fill the 256-float OOB source region at taps+ZOFF.
__global__ void taps_kernel(const float* __restrict__ wh, const float* __restrict__ ww,
                            const float* __restrict__ r, float* __restrict__ taps) {
    int c = threadIdx.x;
    if (c >= C) return;
    taps[ZOFF + c]     = 0.f;   // zero region for OOB staging reads
    taps[ZOFF + C + c] = 0.f;
    float rv = fmaxf(r[0], 1.0f);  // jnp.clip(r, 1.0)
    float eh[NT], ew[NT];
    for (int j = 0; j < NT; ++j) { eh[j] = 0.f; ew[j] = 0.f; }
    for (int i = 0; i < KT; ++i) {
        float kpos  = (float)(i - KT / 2);
        float delta = kpos * rv;
        float d0f   = floorf(delta);
        float fr    = delta - d0f;
        int   j0    = (int)d0f + M;
        float whv = wh[c * KT + i];
        float wwv = ww[c * KT + i];
        if (j0 >= 0 && j0 < NT)         { eh[j0]   += (1.f - fr) * whv; ew[j0]   += (1.f - fr) * wwv; }
        if (j0 + 1 >= 0 && j0 + 1 < NT) { eh[j0+1] += fr * whv;         ew[j0+1] += fr * wwv; }
    }
    for (int j = 0; j < NT; ++j) {
        taps[c * NT + j]          = eh[j];
        taps[C * NT + c * NT + j] = ew[j];
    }
}

__global__ __launch_bounds__(BLOCK) void deform_axial_kernel(
    const float* __restrict__ x, const float* __restrict__ taps,
    float* __restrict__ out) {
    __shared__ float lds[LDS_FLOATS];   // 45,056 B -> 3 blocks/CU

    const int bid   = blockIdx.x;        // 0..2047
    const int p     = bid >> 1;          // plane (b*C + c) -- block-uniform
    const int whf   = bid & 1;           // W-half: quads [28*whf, 28*whf+28)
    const int qb0   = whf * OQ - 2;      // first STAGED quad (may be -2)
    const int c     = p & (C - 1);       // uniform -> taps via scalar loads
    const int tid   = threadIdx.x;
    const int wave  = tid >> 6;
    const int lane  = tid & 63;
    const bool producer = (wave == 4);   // wave-uniform role split

    const long base = (long)p * (H * W);
    const float* __restrict__ xp = x + base;

    // per-channel effective taps: block-uniform address -> SGPRs
    float eh[NT], ew[NT];
    const float* __restrict__ ehp = taps + c * NT;
    const float* __restrict__ ewp = taps + C * NT + c * NT;
#pragma unroll
    for (int j = 0; j < NT; ++j) { eh[j] = ehp[j]; ew[j] = ewp[j]; }
    const float ws6 = ew[6] + 1.0f;   // center W-tap with identity folded in
    // drain so the producer's vmcnt bookkeeping starts from 0 outstanding
    asm volatile("s_waitcnt vmcnt(0)" ::: "memory");

    const float* zbase = taps + ZOFF + lane * 4;  // per-lane 16B zero slot
    float* const buf0 = lds;
    float* const buf1 = lds + BUF_FLOATS;

    // ---- producer: stage tile t's 44-row x 32-quad window, 1 DMA per row.
    // Per-lane source redirect handles BOTH row-OOB and col-OOB (true W edge):
    // LDS gets zeros there, so consumers need no boundary checks at all.
    auto STAGE = [&](float* bufb, int t) {
        const int h0 = t * TH;
        const int sq = qb0 + lane;                    // staged quad, -2..29|26..57
        const bool cv = (unsigned)sq < (unsigned)(W / 4);
#pragma unroll
        for (int row = 0; row < SROWS; ++row) {
            const int grow = h0 - M + row;
            const bool vr  = cv & ((unsigned)grow < (unsigned)H);
            const float* src = vr ? (xp + grow * W + sq * 4) : zbase;
            float* dst = bufb + row * RFLOATS;        // wave-uniform
            if (lane < SQ) {
                __builtin_amdgcn_global_load_lds((gbl_u32*)src, (lds_u32*)dst, 16, 0, 0);
            }
        }
    };

    auto BAR = []() {
        asm volatile("" ::: "memory");
        __builtin_amdgcn_s_barrier();
        asm volatile("" ::: "memory");
    };

    // consumer geometry (threads 0..223)
    const int cq = tid % OQ;        // output quad within half, 0..27
    const int rg = tid / OQ;        // row group 0..7
    const int r0 = rg * RPT;        // first output row within tile (0..28)
    const float4 zero4 = make_float4(0.f, 0.f, 0.f, 0.f);

    // ---- consumer: compute tile t from buffer, store (4 stores/thread).
    // All LDS reads unconditional: center quad = cq+2, sides cq+2+d in [0,32).
    auto COMPUTE = [&](const float* ldsb, int t) {
        const int h0 = t * TH;
        float4 acc[RPT];
#pragma unroll
        for (int k = 0; k < RPT; ++k) acc[k] = zero4;

#pragma unroll
        for (int s = 0; s < WROWS; ++s) {
            const float* rowp = &ldsb[(r0 + s) * RFLOATS];
            const float4 q = *reinterpret_cast<const float4*>(rowp + (cq + 2) * 4);

            // H-axis: streamed row s is tap j = s-k for output row k
#pragma unroll
            for (int k = 0; k < RPT; ++k) {
                const int j = s - k;
                if (j >= 0 && j < NT) {
                    const float wgt = eh[j];
                    acc[k].x = fmaf(wgt, q.x, acc[k].x);
                    acc[k].y = fmaf(wgt, q.y, acc[k].y);
                    acc[k].z = fmaf(wgt, q.z, acc[k].z);
                    acc[k].w = fmaf(wgt, q.w, acc[k].w);
                }
            }

            // center row for output k = s - M: W-conv (identity folded into ws6).
            // Source quad d (-2..2), elem m -> acc elem e uses tap j = 4d+m-e+6.
            if (s >= M && s < M + RPT) {
                const int k = s - M;
                float4& a = acc[k];

                {   // d = -2: 3 FMAs
                    const float4 qd = *reinterpret_cast<const float4*>(rowp + (cq + 0) * 4);
                    a.x = fmaf(ew[0], qd.z, a.x);
                    a.x = fmaf(ew[1], qd.w, a.x);
                    a.y = fmaf(ew[0], qd.w, a.y);
                }
                {   // d = -1: 15 FMAs (j = m - e + 2)
                    const float4 qd = *reinterpret_cast<const float4*>(rowp + (cq + 1) * 4);
                    a.x = fmaf(ew[2], qd.x, a.x); a.y = fmaf(ew[1], qd.x, a.y); a.z = fmaf(ew[0], qd.x, a.z);
                    a.x = fmaf(ew[3], qd.y, a.x); a.y = fmaf(ew[2], qd.y, a.y); a.z = fmaf(ew[1], qd.y, a.z); a.w = fmaf(ew[0], qd.y, a.w);
                    a.x = fmaf(ew[4], qd.z, a.x); a.y = fmaf(ew[3], qd.z, a.y); a.z = fmaf(ew[2], qd.z, a.z); a.w = fmaf(ew[1], qd.z, a.w);
                    a.x = fmaf(ew[5], qd.w, a.x); a.y = fmaf(ew[4], qd.w, a.y); a.z = fmaf(ew[3], qd.w, a.z); a.w = fmaf(ew[2], qd.w, a.w);
                }
                {   // d = 0: 16 FMAs (j = m - e + 6), diagonal uses ws6 = ew[6]+1
                    a.x = fmaf(ws6,   q.x, a.x); a.y = fmaf(ew[5], q.x, a.y); a.z = fmaf(ew[4], q.x, a.z); a.w = fmaf(ew[3], q.x, a.w);
                    a.x = fmaf(ew[7], q.y, a.x); a.y = fmaf(ws6,   q.y, a.y); a.z = fmaf(ew[5], q.y, a.z); a.w = fmaf(ew[4], q.y, a.w);
                    a.x = fmaf(ew[8], q.z, a.x); a.y = fmaf(ew[7], q.z, a.y); a.z = fmaf(ws6,   q.z, a.z); a.w = fmaf(ew[5], q.z, a.w);
                    a.x = fmaf(ew[9], q.w, a.x); a.y = fmaf(ew[8], q.w, a.y); a.z = fmaf(ew[7], q.w, a.z); a.w = fmaf(ws6,   q.w, a.w);
                }
                {   // d = +1: 15 FMAs (j = m - e + 10)
                    const float4 qd = *reinterpret_cast<const float4*>(rowp + (cq + 3) * 4);
                    a.x = fmaf(ew[10], qd.x, a.x); a.y = fmaf(ew[9],  qd.x, a.y); a.z = fmaf(ew[8],  qd.x, a.z); a.w = fmaf(ew[7],  qd.x, a.w);
                    a.x = fmaf(ew[11], qd.y, a.x); a.y = fmaf(ew[10], qd.y, a.y); a.z = fmaf(ew[9],  qd.y, a.z); a.w = fmaf(ew[8],  qd.y, a.w);
                    a.x = fmaf(ew[12], qd.z, a.x); a.y = fmaf(ew[11], qd.z, a.y); a.z = fmaf(ew[10], qd.z, a.z); a.w = fmaf(ew[9],  qd.z, a.w);
                                                   a.y = fmaf(ew[12], qd.w, a.y); a.z = fmaf(ew[11], qd.w, a.z); a.w = fmaf(ew[10], qd.w, a.w);
                }
                {   // d = +2: 3 FMAs (j = m - e + 14)
                    const float4 qd = *reinterpret_cast<const float4*>(rowp + (cq + 4) * 4);
                    a.z = fmaf(ew[12], qd.x, a.z);
                    a.w = fmaf(ew[11], qd.x, a.w);
                    a.w = fmaf(ew[12], qd.y, a.w);
                }
            }
        }

        float* outp = out + base + (long)(h0 + r0) * W + (whf * OQ + cq) * 4;
#pragma unroll
        for (int k = 0; k < RPT; ++k) {
            *reinterpret_cast<float4*>(outp + k * W) = acc[k];
        }
    };

    // ---- producer/consumer pipeline: ONE barrier per tile ----
    // Invariant at tile-t barrier entry: buf[t&1] holds window t, complete.
    if (producer) {
        STAGE(buf0, 0);
        asm volatile("s_waitcnt vmcnt(0)" ::: "memory");  // window 0 landed
    }
    BAR();

#pragma unroll
    for (int t = 0; t < NTPB; ++t) {
        if (producer) {
            if (t + 1 < NTPB) {
                STAGE((t & 1) ? buf0 : buf1, t + 1);      // buffer consumers aren't reading
                asm volatile("s_waitcnt vmcnt(0)" ::: "memory");  // producer-only wait
            }
        } else if (tid < NCONS) {
            COMPUTE((t & 1) ? buf1 : buf0, t);            // read buf[t&1] + stores
        }
        BAR();                                            // window t+1 ready; reads done
    }
}

extern "C" void kernel_launch(void* const* d_in, const int* in_sizes, int n_in,
                              void* d_out, int out_size, void* d_ws, size_t ws_size,
                              hipStream_t stream) {
    const float* x  = (const float*)d_in[0];
    const float* wh = (const float*)d_in[1];
    const float* ww = (const float*)d_in[2];
    const float* r  = (const float*)d_in[3];
    float* out  = (float*)d_out;
    float* taps = (float*)d_ws;  // needs (2*C*NT + 256)*4 = 14,336 bytes

    hipLaunchKernelGGL(taps_kernel, dim3(1), dim3(C), 0, stream, wh, ww, r, taps);
    hipLaunchKernelGGL(deform_axial_kernel, dim3(2 * B * C), dim3(BLOCK),
                       0, stream, x, taps, out);
}

// Round 21
// 91.229 us; speedup vs baseline: 1.1549x; 1.1549x over previous
//
#include <hip/hip_runtime.h>
#include <stdint.h>

// DNAS_DeformAxialDW: out = x + axial-deform-DW-conv_H(x) + axial-deform-DW-conv_W(x)
// Scalar fractional dilation r => each 7-tap conv folds into 13 integer taps with
// per-channel effective weights (precomputed into d_ws by taps_kernel).
//
// R18 90.8 BEST: producer-consumer wave split (wave 7 stages 28 rows/tile +
//     absorbs vmcnt(0); waves 0-6 compute; one barrier per tile; dbuf 51KB,
//     3 blk/CU = 21 consumer waves). HBM 54%, LDS 47%, VALU 22%.
// R19 94.7 (RPT=4 full-W: 1 blk/CU); R20 105.4 (W-split: consumer waves
//     halved) => consumer-wave count is the latency-hiding currency; RPT=4
//     branch closed.
// R21: R18 + s_setprio(1) around consumer COMPUTE (T5: needs wave role
//      diversity, which producer/consumer split provides; m191 +4-7% analog).
//      Priority dropped to 0 before each barrier so arbitration stays fair.

namespace {
constexpr int B = 8, C = 128, H = 224, W = 224;
constexpr int KT = 7;              // original taps
constexpr int M  = 6;              // max |integer offset| (r in [1,2])
constexpr int NT = 2 * M + 1;      // 13 effective integer taps
constexpr int TH = 16;             // output rows per tile
constexpr int NTPB = 7;            // tiles per block (half-plane: 112 rows)
constexpr int SROWS = TH + 2 * M;  // 28 staged rows
constexpr int WQ = W / 4;          // 56 quads per row
constexpr int BLOCK = 512;         // 7 consumer waves (448 thr) + 1 producer wave
constexpr int RPT = 2;             // output rows per thread
constexpr int WROWS = RPT + 2 * M; // 14 window rows per thread
constexpr int RSTRIDE = 228;       // padded LDS row stride (floats), 16B aligned
constexpr int BUF_FLOATS = SROWS * RSTRIDE;   // 6384 floats = 25,536 B
constexpr int LDS_FLOATS = 2 * BUF_FLOATS;    // 51,072 B -> 3 blocks/CU
constexpr int ZOFF = 2 * C * NT;   // zeros region offset in d_ws (floats) = 3328
}

typedef __attribute__((address_space(3))) uint32_t lds_u32;
typedef __attribute__((address_space(1))) const uint32_t gbl_u32;

// Fold bilinear fractional taps into integer-offset effective weights; also
// zero-fill the 256-float OOB source region at taps+ZOFF.
__global__ void taps_kernel(const float* __restrict__ wh, const float* __restrict__ ww,
                            const float* __restrict__ r, float* __restrict__ taps) {
    int c = threadIdx.x;
    if (c >= C) return;
    taps[ZOFF + c]     = 0.f;   // zero region for OOB staging reads
    taps[ZOFF + C + c] = 0.f;
    float rv = fmaxf(r[0], 1.0f);  // jnp.clip(r, 1.0)
    float eh[NT], ew[NT];
    for (int j = 0; j < NT; ++j) { eh[j] = 0.f; ew[j] = 0.f; }
    for (int i = 0; i < KT; ++i) {
        float kpos  = (float)(i - KT / 2);
        float delta = kpos * rv;
        float d0f   = floorf(delta);
        float fr    = delta - d0f;
        int   j0    = (int)d0f + M;
        float whv = wh[c * KT + i];
        float wwv = ww[c * KT + i];
        if (j0 >= 0 && j0 < NT)         { eh[j0]   += (1.f - fr) * whv; ew[j0]   += (1.f - fr) * wwv; }
        if (j0 + 1 >= 0 && j0 + 1 < NT) { eh[j0+1] += fr * whv;         ew[j0+1] += fr * wwv; }
    }
    for (int j = 0; j < NT; ++j) {
        taps[c * NT + j]          = eh[j];
        taps[C * NT + c * NT + j] = ew[j];
    }
}

__global__ __launch_bounds__(BLOCK) void deform_axial_kernel(
    const float* __restrict__ x, const float* __restrict__ taps,
    float* __restrict__ out) {
    __shared__ float lds[LDS_FLOATS];   // 51,072 B -> 3 blocks/CU

    const int bid   = blockIdx.x;        // 0..2047
    const int p     = bid >> 1;          // plane (b*C + c) -- block-uniform
    const int half  = bid & 1;           // 0: rows 0..111, 1: rows 112..223
    const int hbase = half * (H / 2);
    const int c     = p & (C - 1);       // uniform -> taps via scalar loads
    const int tid   = threadIdx.x;
    const int wave  = tid >> 6;
    const int lane  = tid & 63;
    const bool producer = (wave == 7);   // wave-uniform role split

    const long base = (long)p * (H * W);
    const float* __restrict__ xp = x + base;

    // per-channel effective taps: block-uniform address -> SGPRs
    float eh[NT], ew[NT];
    const float* __restrict__ ehp = taps + c * NT;
    const float* __restrict__ ewp = taps + C * NT + c * NT;
#pragma unroll
    for (int j = 0; j < NT; ++j) { eh[j] = ehp[j]; ew[j] = ewp[j]; }
    const float ws6 = ew[6] + 1.0f;   // center W-tap with identity folded in
    // drain so the producer's vmcnt bookkeeping starts from 0 outstanding
    asm volatile("s_waitcnt vmcnt(0)" ::: "memory");

    const float* zbase = taps + ZOFF + lane * 4;  // per-lane 16B zero slot
    float* const buf0 = lds;
    float* const buf1 = lds + BUF_FLOATS;

    // ---- producer: stage tile t's 28-row window, 1 DMA per row (28 instrs) ----
    auto STAGE = [&](float* bufb, int t) {
        const int h0 = hbase + t * TH;
#pragma unroll
        for (int row = 0; row < SROWS; ++row) {
            const int grow = h0 - M + row;
            const bool vr  = (unsigned)grow < (unsigned)H;
            const float* src = vr ? (xp + grow * W + lane * 4) : zbase;
            float* dst = bufb + row * RSTRIDE;        // wave-uniform
            if (lane < 56) {
                __builtin_amdgcn_global_load_lds((gbl_u32*)src, (lds_u32*)dst, 16, 0, 0);
            }
        }
    };

    auto BAR = []() {
        asm volatile("" ::: "memory");
        __builtin_amdgcn_s_barrier();
        asm volatile("" ::: "memory");
    };

    // consumer geometry (threads 0..447; R15 mapping)
    const int cq = tid % WQ;        // column quad 0..55
    const int rg = tid / WQ;        // row group 0..7 (producer wave: ignored)
    const int r0 = rg * RPT;        // first output row within tile
    const float4 zero4 = make_float4(0.f, 0.f, 0.f, 0.f);

    // ---- consumer: compute tile t from buffer, store (2 stores/thread) ----
    auto COMPUTE = [&](const float* ldsb, int t) {
        const int h0 = hbase + t * TH;
        float4 acc[RPT];
#pragma unroll
        for (int k = 0; k < RPT; ++k) acc[k] = zero4;

#pragma unroll
        for (int s = 0; s < WROWS; ++s) {
            const float4 q = *reinterpret_cast<const float4*>(&ldsb[(r0 + s) * RSTRIDE + cq * 4]);

            // H-axis: streamed row s is tap j = s-k for output row k
#pragma unroll
            for (int k = 0; k < RPT; ++k) {
                const int j = s - k;
                if (j >= 0 && j < NT) {
                    const float wgt = eh[j];
                    acc[k].x = fmaf(wgt, q.x, acc[k].x);
                    acc[k].y = fmaf(wgt, q.y, acc[k].y);
                    acc[k].z = fmaf(wgt, q.z, acc[k].z);
                    acc[k].w = fmaf(wgt, q.w, acc[k].w);
                }
            }

            // center row for output k = s - M: W-conv (identity folded into ws6).
            // Source quad d (-2..2), elem m -> acc elem e uses tap j = 4d+m-e+6.
            if (s >= M && s < M + RPT) {
                const int k = s - M;
                const float* crow = &ldsb[(r0 + s) * RSTRIDE];
                float4& a = acc[k];

                {   // d = -2: 3 FMAs
                    const float4 qd = (cq >= 2) ? *reinterpret_cast<const float4*>(crow + (cq - 2) * 4) : zero4;
                    a.x = fmaf(ew[0], qd.z, a.x);
                    a.x = fmaf(ew[1], qd.w, a.x);
                    a.y = fmaf(ew[0], qd.w, a.y);
                }
                {   // d = -1: 15 FMAs (j = m - e + 2)
                    const float4 qd = (cq >= 1) ? *reinterpret_cast<const float4*>(crow + (cq - 1) * 4) : zero4;
                    a.x = fmaf(ew[2], qd.x, a.x); a.y = fmaf(ew[1], qd.x, a.y); a.z = fmaf(ew[0], qd.x, a.z);
                    a.x = fmaf(ew[3], qd.y, a.x); a.y = fmaf(ew[2], qd.y, a.y); a.z = fmaf(ew[1], qd.y, a.z); a.w = fmaf(ew[0], qd.y, a.w);
                    a.x = fmaf(ew[4], qd.z, a.x); a.y = fmaf(ew[3], qd.z, a.y); a.z = fmaf(ew[2], qd.z, a.z); a.w = fmaf(ew[1], qd.z, a.w);
                    a.x = fmaf(ew[5], qd.w, a.x); a.y = fmaf(ew[4], qd.w, a.y); a.z = fmaf(ew[3], qd.w, a.z); a.w = fmaf(ew[2], qd.w, a.w);
                }
                {   // d = 0: 16 FMAs (j = m - e + 6), diagonal uses ws6 = ew[6]+1
                    a.x = fmaf(ws6,   q.x, a.x); a.y = fmaf(ew[5], q.x, a.y); a.z = fmaf(ew[4], q.x, a.z); a.w = fmaf(ew[3], q.x, a.w);
                    a.x = fmaf(ew[7], q.y, a.x); a.y = fmaf(ws6,   q.y, a.y); a.z = fmaf(ew[5], q.y, a.z); a.w = fmaf(ew[4], q.y, a.w);
                    a.x = fmaf(ew[8], q.z, a.x); a.y = fmaf(ew[7], q.z, a.y); a.z = fmaf(ws6,   q.z, a.z); a.w = fmaf(ew[5], q.z, a.w);
                    a.x = fmaf(ew[9], q.w, a.x); a.y = fmaf(ew[8], q.w, a.y); a.z = fmaf(ew[7], q.w, a.z); a.w = fmaf(ws6,   q.w, a.w);
                }
                {   // d = +1: 15 FMAs (j = m - e + 10)
                    const float4 qd = (cq <= WQ - 2) ? *reinterpret_cast<const float4*>(crow + (cq + 1) * 4) : zero4;
                    a.x = fmaf(ew[10], qd.x, a.x); a.y = fmaf(ew[9],  qd.x, a.y); a.z = fmaf(ew[8],  qd.x, a.z); a.w = fmaf(ew[7],  qd.x, a.w);
                    a.x = fmaf(ew[11], qd.y, a.x); a.y = fmaf(ew[10], qd.y, a.y); a.z = fmaf(ew[9],  qd.y, a.z); a.w = fmaf(ew[8],  qd.y, a.w);
                    a.x = fmaf(ew[12], qd.z, a.x); a.y = fmaf(ew[11], qd.z, a.y); a.z = fmaf(ew[10], qd.z, a.z); a.w = fmaf(ew[9],  qd.z, a.w);
                                                   a.y = fmaf(ew[12], qd.w, a.y); a.z = fmaf(ew[11], qd.w, a.z); a.w = fmaf(ew[10], qd.w, a.w);
                }
                {   // d = +2: 3 FMAs (j = m - e + 14)
                    const float4 qd = (cq <= WQ - 3) ? *reinterpret_cast<const float4*>(crow + (cq + 2) * 4) : zero4;
                    a.z = fmaf(ew[12], qd.x, a.z);
                    a.w = fmaf(ew[11], qd.x, a.w);
                    a.w = fmaf(ew[12], qd.y, a.w);
                }
            }
        }

        float* outp = out + base + (long)(h0 + r0) * W + cq * 4;
#pragma unroll
        for (int k = 0; k < RPT; ++k) {
            *reinterpret_cast<float4*>(outp + k * W) = acc[k];
        }
    };

    // ---- producer/consumer pipeline: ONE barrier per tile ----
    // Invariant at tile-t barrier entry: buf[t&1] holds window t, complete.
    if (producer) {
        STAGE(buf0, 0);
        asm volatile("s_waitcnt vmcnt(0)" ::: "memory");  // window 0 landed
    }
    BAR();

#pragma unroll
    for (int t = 0; t < NTPB; ++t) {
        if (producer) {
            if (t + 1 < NTPB) {
                STAGE((t & 1) ? buf0 : buf1, t + 1);      // buffer consumers aren't reading
                asm volatile("s_waitcnt vmcnt(0)" ::: "memory");  // producer-only wait
            }
        } else {
            // T5: favor compute waves while producer waves issue DMA / wait.
            __builtin_amdgcn_s_setprio(1);
            COMPUTE((t & 1) ? buf1 : buf0, t);            // read buf[t&1] + stores
            __builtin_amdgcn_s_setprio(0);
        }
        BAR();                                            // window t+1 ready; reads done
    }
}

extern "C" void kernel_launch(void* const* d_in, const int* in_sizes, int n_in,
                              void* d_out, int out_size, void* d_ws, size_t ws_size,
                              hipStream_t stream) {
    const float* x  = (const float*)d_in[0];
    const float* wh = (const float*)d_in[1];
    const float* ww = (const float*)d_in[2];
    const float* r  = (const float*)d_in[3];
    float* out  = (float*)d_out;
    float* taps = (float*)d_ws;  // needs (2*C*NT + 256)*4 = 14,336 bytes

    hipLaunchKernelGGL(taps_kernel, dim3(1), dim3(C), 0, stream, wh, ww, r, taps);
    hipLaunchKernelGGL(deform_axial_kernel, dim3(2 * B * C), dim3(BLOCK),
                       0, stream, x, taps, out);
}